// Round 6
// baseline (138684.180 us; speedup 1.0000x reference)
//
#include <hip/hip_runtime.h>
#include <cstdint>
#include <cstddef>

// Reverse LSTM, B=128, T=2048, H=512, input dim 1.
// 256 WGs, 1 per CU (LDS-capped). SELF-ORGANIZED by XCD: g = s_getreg(XCC_ID),
// p = atomicAdd rank 0..31 within the XCD. All 32 WGs of a group share one
// XCD's L2, so the h exchange uses sc0 (L1-bypass, L2-served) stores/loads —
// never L3/HBM. Round-4 PMC showed the sc1 path ran the exchange at HBM
// (FETCH 2 MB/step, 6.5 us/step); this keeps it at ~200cy L2 RTT.
// Tag-in-payload 8B words (tag<<32 | dual-bf16), depth-2 by step parity.
// Discovery: sentinel tag-dword per 64B line (4/lane) with s_sleep backoff,
// then one bulk 16x dwordx4 tag-verified load. Wh persistent in LDS (dual-bf16
// hi/lo, 3-MFMA ~f32 product). c-state in registers.
// Safety: poll(t+1) observes tags(t) from ALL group WGs incl. own WG's 4 waves;
// each tag(t) store value-depends on that producer's gate(t), which depends on
// its zbuf reads(t) and its h(t-1) loads => both the depth-2 hexq WAR and the
// zbuf WAR are ordered by the poll alone (BAR2 removed). BAR1 (lgkm-only)
// protects zbuf RAW. Tags at a parity are {t-3, t-1, 0xAA-poison}: exact
// equality-wait, poison never matches, no hexq init needed.

#define TSEQ 2048
#define HID  512
#define NGRP 8
#define MB   16      // batches per group
#define SH   16      // hidden units per WG
#define NCOL 64      // 4 gates * SH
#define WSTR 520     // padded k-stride (bf16 elems)
#define ZSTR 65      // padded zbuf col stride (dwords)

typedef float f32x4 __attribute__((ext_vector_type(4)));
typedef short bf16x8 __attribute__((ext_vector_type(8)));
typedef uint32_t u32x4 __attribute__((ext_vector_type(4)));

__device__ __forceinline__ unsigned short f2bf(float f) {
  uint32_t u = __float_as_uint(f);
  u += 0x7fffu + ((u >> 16) & 1u);   // RNE
  return (unsigned short)(u >> 16);
}
__device__ __forceinline__ float bf2f(unsigned short b) {
  return __uint_as_float(((uint32_t)b) << 16);
}
__device__ __forceinline__ float sigm(float z) {
  return 1.0f / (1.0f + __expf(-z));
}
__device__ __forceinline__ float tanh_f(float z) {
  float a = fabsf(z);
  float e = __expf(-2.0f * a);
  float t = (1.0f - e) / (1.0f + e);
  return copysignf(t, z);
}

extern "C" __global__ void __launch_bounds__(256, 1)
lstm_rev_kernel(const float* __restrict__ x, const float* __restrict__ Wi,
                const float* __restrict__ Wh, const float* __restrict__ bias,
                float* __restrict__ out, uint32_t* __restrict__ ws)
{
  extern __shared__ char smem[];
  unsigned short* wh_hi = (unsigned short*)smem;           // [NCOL][WSTR] bf16 hi
  unsigned short* wh_lo = wh_hi + NCOL * WSTR;             // [NCOL][WSTR] bf16 lo
  float* zbuf = (float*)(wh_lo + NCOL * WSTR);             // [4][MB][ZSTR] partial z
  float* wi_l = zbuf + 4 * MB * ZSTR;                      // [NCOL]
  float* bi_l = wi_l + NCOL;                               // [NCOL]

  const int tid = threadIdx.x;

  // ---- self-organize: group = my XCD, part = rank within XCD ----
  __shared__ uint32_t s_gp;
  if (tid == 0) {
    uint32_t xcd;
    asm volatile("s_getreg_b32 %0, hwreg(HW_REG_XCC_ID)" : "=s"(xcd));
    xcd &= 7;
    uint32_t r = atomicAdd(&ws[xcd * 16], 1u) & 31;   // device-scope; 32 WGs/XCD
    s_gp = (xcd << 8) | r;
  }
  __syncthreads();
  const int g = (int)(s_gp >> 8);   // batch group == XCD id
  const int p = (int)(s_gp & 255);  // column part 0..31

  unsigned long long* hexq = (unsigned long long*)(ws + 1024);  // [2][NGRP][MB][HID]

  // ---- one-time: stage Wi/bias and the dual-bf16 Wh slice into LDS ----
  for (int c = tid; c < NCOL; c += 256) {
    int G = c >> 4, u = c & 15;
    int j = G * HID + p * SH + u;
    wi_l[c] = Wi[j];
    bi_l[c] = bias[j];
  }
  for (int idx = tid; idx < NCOL * HID; idx += 256) {
    int col = idx & (NCOL - 1);
    int k   = idx >> 6;
    int G = col >> 4, u = col & 15;
    float v = Wh[(size_t)k * (4 * HID) + G * HID + p * SH + u];
    unsigned short hi = f2bf(v);
    unsigned short lo = f2bf(v - bf2f(hi));
    wh_hi[col * WSTR + k] = hi;
    wh_lo[col * WSTR + k] = lo;
  }
  __syncthreads();

  const int lane = tid & 63;
  const int wave = tid >> 6;     // MFMA k-split: wave w owns k in [w*128, w*128+128)
  const int arow = lane & 15;    // A row (batch) / D col
  const int kgrp = lane >> 4;    // 0..3
  const int gb = tid >> 4;       // gate-phase batch 0..15
  const int gu = tid & 15;       // gate-phase hidden unit 0..15

  float wiv[4], biv[4];
  #pragma unroll
  for (int G = 0; G < 4; ++G) { wiv[G] = wi_l[G * 16 + gu]; biv[G] = bi_l[G * 16 + gu]; }

  // consumer base (this lane's k-slice of batch arow), per parity:
  const size_t cb0 = ((size_t)(0 * NGRP + g) * MB + arow) * HID + wave * 128 + kgrp * 8;
  const size_t cb1 = ((size_t)(1 * NGRP + g) * MB + arow) * HID + wave * 128 + kgrp * 8;
  // producer slot (this thread's (batch gb, unit p*SH+gu)), per parity:
  const size_t pw0 = ((size_t)(0 * NGRP + g) * MB + gb) * HID + p * SH + gu;
  const size_t pw1 = ((size_t)(1 * NGRP + g) * MB + gb) * HID + p * SH + gu;

  float cst = 0.0f;
  const float* xrow = x + (size_t)(g * MB + gb) * TSEQ;
  float* orow = out + (size_t)(g * MB + gb) * TSEQ * HID + p * SH + gu;

  for (int t = 0; t < TSEQ; ++t) {
    float xv = xrow[TSEQ - 1 - t];
    float xwb[4];
    #pragma unroll
    for (int G = 0; G < 4; ++G) xwb[G] = fmaf(xv, wiv[G], biv[G]);

    if (t > 0) {
      const uint32_t need = (uint32_t)(t - 1);
      const unsigned long long* pb = hexq + (((t - 1) & 1) ? cb1 : cb0);

      // ---- discovery: tag dword of each of this lane's 4 lines (L2, sc0) ----
      {
        uint32_t g0, g1, g2, g3;
        while (true) {
          asm volatile(
            "global_load_dword %0, %4, off offset:4 sc0\n\t"
            "global_load_dword %1, %4, off offset:260 sc0\n\t"
            "global_load_dword %2, %4, off offset:516 sc0\n\t"
            "global_load_dword %3, %4, off offset:772 sc0\n\t"
            "s_waitcnt vmcnt(0)"
            : "=&v"(g0), "=&v"(g1), "=&v"(g2), "=&v"(g3)
            : "v"(pb) : "memory");
          bool ok = (g0 == need) && (g1 == need) && (g2 == need) && (g3 == need);
          if (__all((int)ok)) break;
          __builtin_amdgcn_s_sleep(1);   // ~64cy backoff: cut L2 poll congestion
        }
      }

      // ---- bulk: 16x dwordx4 (all 32 u64 words), tag-verified, retry rare ----
      u32x4 Q[16];
      while (true) {
        asm volatile(
          "global_load_dwordx4 %0,  %16, off sc0\n\t"
          "global_load_dwordx4 %1,  %16, off offset:16 sc0\n\t"
          "global_load_dwordx4 %2,  %16, off offset:32 sc0\n\t"
          "global_load_dwordx4 %3,  %16, off offset:48 sc0\n\t"
          "global_load_dwordx4 %4,  %16, off offset:256 sc0\n\t"
          "global_load_dwordx4 %5,  %16, off offset:272 sc0\n\t"
          "global_load_dwordx4 %6,  %16, off offset:288 sc0\n\t"
          "global_load_dwordx4 %7,  %16, off offset:304 sc0\n\t"
          "global_load_dwordx4 %8,  %16, off offset:512 sc0\n\t"
          "global_load_dwordx4 %9,  %16, off offset:528 sc0\n\t"
          "global_load_dwordx4 %10, %16, off offset:544 sc0\n\t"
          "global_load_dwordx4 %11, %16, off offset:560 sc0\n\t"
          "global_load_dwordx4 %12, %16, off offset:768 sc0\n\t"
          "global_load_dwordx4 %13, %16, off offset:784 sc0\n\t"
          "global_load_dwordx4 %14, %16, off offset:800 sc0\n\t"
          "global_load_dwordx4 %15, %16, off offset:816 sc0\n\t"
          "s_waitcnt vmcnt(0)"
          : "=&v"(Q[0]), "=&v"(Q[1]), "=&v"(Q[2]), "=&v"(Q[3]),
            "=&v"(Q[4]), "=&v"(Q[5]), "=&v"(Q[6]), "=&v"(Q[7]),
            "=&v"(Q[8]), "=&v"(Q[9]), "=&v"(Q[10]), "=&v"(Q[11]),
            "=&v"(Q[12]), "=&v"(Q[13]), "=&v"(Q[14]), "=&v"(Q[15])
          : "v"(pb) : "memory");
        bool ok = true;
        #pragma unroll
        for (int i = 0; i < 16; ++i)
          ok = ok && (Q[i][1] == need) && (Q[i][3] == need);
        if (__all((int)ok)) break;
      }

      // ---- z partial = h(t-1) @ Wh_slice, dual-bf16 MFMA, k-split by wave ----
      f32x4 acc[4] = {{0,0,0,0},{0,0,0,0},{0,0,0,0},{0,0,0,0}};
      #pragma unroll
      for (int cc = 0; cc < 4; ++cc) {
        bf16x8 ahi, alo;
        #pragma unroll
        for (int j = 0; j < 8; ++j) {
          uint32_t pl = Q[cc * 4 + (j >> 1)][(j & 1) << 1];
          ahi[j] = (short)(pl >> 16);
          alo[j] = (short)(pl & 0xffffu);
        }
        const int kb = wave * 128 + kgrp * 8 + cc * 32;
        #pragma unroll
        for (int n = 0; n < 4; ++n) {
          const int col = n * 16 + arow;
          bf16x8 bhi = *(const bf16x8*)(wh_hi + col * WSTR + kb);
          bf16x8 blo = *(const bf16x8*)(wh_lo + col * WSTR + kb);
          acc[n] = __builtin_amdgcn_mfma_f32_16x16x32_bf16(ahi, bhi, acc[n], 0, 0, 0);
          acc[n] = __builtin_amdgcn_mfma_f32_16x16x32_bf16(ahi, blo, acc[n], 0, 0, 0);
          acc[n] = __builtin_amdgcn_mfma_f32_16x16x32_bf16(alo, bhi, acc[n], 0, 0, 0);
        }
      }
      // spill partial z: D layout col=lane&15, row=(lane>>4)*4+reg  [m89-verified]
      #pragma unroll
      for (int n = 0; n < 4; ++n) {
        #pragma unroll
        for (int j = 0; j < 4; ++j) {
          int row = kgrp * 4 + j;
          zbuf[(wave * MB + row) * ZSTR + n * 16 + arow] = acc[n][j];
        }
      }
    }
    // BAR1: zbuf(t) complete before gate reads. lgkm-only (no vmcnt drain).
    asm volatile("s_waitcnt lgkmcnt(0)\n\ts_barrier" ::: "memory");

    // ---- gate phase: one thread per (batch, hidden unit) ----
    float z[4];
    #pragma unroll
    for (int G = 0; G < 4; ++G) {
      float s = xwb[G];
      if (t > 0) {
        #pragma unroll
        for (int w = 0; w < 4; ++w) s += zbuf[(w * MB + gb) * ZSTR + G * 16 + gu];
      }
      z[G] = s;
    }
    float ig = sigm(z[0]);
    float fg = sigm(z[1]);
    float gg = tanh_f(z[2]);
    float og = sigm(z[3]);
    cst = fg * cst + ig * gg;
    float h = og * tanh_f(cst);

    // publish h: one 8B word (tag<<32 | dual-bf16), sc0 -> XCD-local L2
    unsigned short hh = f2bf(h);
    unsigned short hl = f2bf(h - bf2f(hh));
    unsigned long long word = ((unsigned long long)(uint32_t)t << 32)
                            | (unsigned long long)(((uint32_t)hh << 16) | (uint32_t)hl);
    unsigned long long* hptr = hexq + ((t & 1) ? pw1 : pw0);
    asm volatile("global_store_dwordx2 %0, %1, off sc0" :: "v"(hptr), "v"(word) : "memory");

    // out store last (nt: no L2 pollution); drains under next step's poll
    __builtin_nontemporal_store(h, &orow[(size_t)t * HID]);
    // No BAR2: next step's poll covers own WG's 4 wave-tags, whose stores
    // value-depend on their zbuf reads of step t => zbuf WAR is ordered.
  }
}

extern "C" void kernel_launch(void* const* d_in, const int* in_sizes, int n_in,
                              void* d_out, int out_size, void* d_ws, size_t ws_size,
                              hipStream_t stream) {
  // inputs: 0=s (unused), 1=x (128x2048 f32), 2=Wi (2048), 3=Wh (512x2048), 4=b (2048)
  const float* x  = (const float*)d_in[1];
  const float* Wi = (const float*)d_in[2];
  const float* Wh = (const float*)d_in[3];
  const float* bs = (const float*)d_in[4];
  float* out = (float*)d_out;
  uint32_t* ws = (uint32_t*)d_ws;

  const size_t SMEM = (size_t)(2 * NCOL * WSTR) * sizeof(unsigned short)
                    + (size_t)(4 * MB * ZSTR) * sizeof(float)
                    + (size_t)(2 * NCOL) * sizeof(float);   // 150,272 B

  hipFuncSetAttribute(reinterpret_cast<const void*>(lstm_rev_kernel),
                      hipFuncAttributeMaxDynamicSharedMemorySize, (int)SMEM);
  hipMemsetAsync(d_ws, 0, 4096, stream);   // zero the XCD rank counters
  // hexq (at +4096) needs no init: 0xAA poison tag never equals a real tag.

  void* args[] = { (void*)&x, (void*)&Wi, (void*)&Wh, (void*)&bs, (void*)&out, (void*)&ws };
  hipLaunchCooperativeKernel(reinterpret_cast<const void*>(lstm_rev_kernel),
                             dim3(256), dim3(256), args, (unsigned)SMEM, stream);
}